// Round 27
// baseline (621.565 us; speedup 1.0000x reference)
//
#include <hip/hip_runtime.h>
#include <float.h>
#include <limits.h>

// Problem constants (fixed by setup_inputs)
static const int BG    = 256;    // graphs
static const int SORTN = 1024;   // bitonic size >= MAXN=1000
static const int DF    = 193;    // 64+64+64+1
static const int K2C   = 27;
static const int K1C   = 3;
static const int NRESC = 973;    // MAXN - K2
static const int PLEN  = 5790;   // 30*193
static const int GPARTS= 8;      // stats split factor
static const int MAXE  = 8192;   // LDS edge capacity >= EPG=7813
static const int MAXN  = 1000;   // max nodes per graph
static const int HLP   = 36;     // LDS half-slice row stride (32 + 4 pad, 16B-aligned)

#define DEV static __device__ __forceinline__

DEV float warp_sum64(float v){
#pragma unroll
  for (int o = 1; o < 64; o <<= 1) v += __shfl_xor(v, o);
  return v;
}
DEV float warp_min64(float v){
#pragma unroll
  for (int o = 1; o < 64; o <<= 1) v = fminf(v, __shfl_xor(v, o));
  return v;
}
DEV float feat_at(const float* __restrict__ x1, const float* __restrict__ x2,
                  const float* __restrict__ x3, const float* __restrict__ x4,
                  int node, int d){
  if (d < 64)  return x1[node*64 + d];
  if (d < 128) return x2[node*64 + (d-64)];
  if (d < 192) return x3[node*64 + (d-128)];
  return x4[node];
}

// ---------------- graph prep ----------------
__global__ __launch_bounds__(256) void k_bounds(const int* __restrict__ batch, int* __restrict__ goff, int NT){
  int i = blockIdx.x*256 + threadIdx.x;
  if (i < NT){
    if (i == 0 || batch[i] != batch[i-1]) goff[batch[i]] = i;
    if (i == NT-1) goff[BG] = NT;
  }
}
__global__ void k_gcount(const int* __restrict__ goff, int* __restrict__ gcount){
  int g = blockIdx.x*256 + threadIdx.x;
  if (g < BG) gcount[g] = goff[g+1] - goff[g];
}

// One block per graph, 1024 threads. Degree count + dis + csr_off + LDS
// scatter + per-node sort + coalesced write-out. All atomics LDS-scope.
__global__ __launch_bounds__(1024) void k_build(const int* __restrict__ rows, const int* __restrict__ cols,
                                                const int* __restrict__ gcount, const int* __restrict__ goff,
                                                float* __restrict__ dis, int* __restrict__ csr_off,
                                                int* __restrict__ csr_src, float* __restrict__ csr_w,
                                                int NT, int E, int epg){
  __shared__ int   lsrc[MAXE];
  __shared__ float lw[MAXE];
  __shared__ int   cnt[1024];
  __shared__ int   offl[1024];
  __shared__ int   cur[1024];
  __shared__ float disl[1024];
  __shared__ int   sm[1024];
  int g = blockIdx.x, tid = threadIdx.x;
  int n = gcount[g], base = goff[g];
  int ebase = g*epg;
  cnt[tid] = 0;
  __syncthreads();
  for (int i = tid; i < epg; i += 1024)
    atomicAdd(&cnt[cols[ebase+i] - base], 1);
  __syncthreads();
  if (tid < n){
    float d = 1.0f / sqrtf((float)cnt[tid] + 1.0f);
    disl[tid] = d;
    dis[base + tid] = d;
  }
  sm[tid] = cnt[tid]; __syncthreads();
  for (int o = 1; o < 1024; o <<= 1){
    int add = (tid >= o) ? sm[tid - o] : 0;
    __syncthreads(); sm[tid] += add; __syncthreads();
  }
  int excl = (tid > 0) ? sm[tid - 1] : 0;
  offl[tid] = excl; cur[tid] = excl;
  __syncthreads();
  if (tid < n) csr_off[base + tid] = ebase + offl[tid];
  if (g == BG - 1 && tid == 0) csr_off[NT] = E;
  for (int i = tid; i < epg; i += 1024){
    int r = rows[ebase + i], c = cols[ebase + i];
    float w = disl[r - base] * disl[c - base];
    int pos = atomicAdd(&cur[c - base], 1);
    lsrc[pos] = r;
    lw[pos]   = w;
  }
  __syncthreads();
  if (tid < n){
    int s0 = offl[tid];
    int s1 = (tid + 1 < n) ? offl[tid + 1] : epg;
    for (int i = s0 + 1; i < s1; i++){
      int ks = lsrc[i]; float kw = lw[i];
      int j = i - 1;
      while (j >= s0 && lsrc[j] > ks){ lsrc[j+1] = lsrc[j]; lw[j+1] = lw[j]; j--; }
      lsrc[j+1] = ks; lw[j+1] = kw;
    }
  }
  __syncthreads();
  for (int i = tid; i < epg; i += 1024){
    csr_src[ebase + i] = lsrc[i];
    csr_w[ebase + i]   = lw[i];
  }
}

// ---------------- low-register GEMM: no prefetch regs, 128-row tile --------
// Staging loads issued between compute phases (short register lifetime);
// __launch_bounds__(256,8) targets <=64 VGPR -> 8 waves/SIMD. Ascending-k
// accumulation, 4x8 blocking. Used for ALL layers (K=128 and K=64).
template<int K>
__global__ __launch_bounds__(256, 8) void k_gemm_lo(const float* __restrict__ X, const float* __restrict__ W,
                                                    float* __restrict__ H, int NT){
  const int BK = 32, KP = 36, NC = K/BK, TR = 128;
  __shared__ __align__(16) float xL[TR*KP];
  __shared__ __align__(16) float wL[BK*64];
  int tid = threadIdx.x;
  int rbase = blockIdx.x * TR;
  int r0 = tid >> 3;
  int cg = (tid & 7) * 8;
  float acc[4][8];
#pragma unroll
  for (int i = 0; i < 4; i++)
#pragma unroll
    for (int j = 0; j < 8; j++) acc[i][j] = 0.f;
  for (int c = 0; c < NC; c++){
    int k0 = c*BK;
    if (c > 0) __syncthreads();
    // stage X chunk (short register lifetime)
#pragma unroll
    for (int q = 0; q < 4; q++){
      int p = q*256 + tid;
      int row = p >> 3, c4 = p & 7;
      int gr = rbase + row;
      float4 v = make_float4(0.f,0.f,0.f,0.f);
      if (gr < NT) v = *((const float4*)&X[(size_t)gr*K + k0 + c4*4]);
      *((float4*)&xL[row*KP + c4*4]) = v;
    }
#pragma unroll
    for (int j = 0; j < 2; j++){
      int i = tid*2 + j;
      int kr = i >> 4, cc = (i & 15)*4;
      float4 v = *((const float4*)&W[(size_t)(k0 + kr)*64 + cc]);
      *((float4*)&wL[kr*64 + cc]) = v;
    }
    __syncthreads();
    for (int kq = 0; kq < BK; kq += 4){
      float4 xr[4];
#pragma unroll
      for (int i = 0; i < 4; i++) xr[i] = *((const float4*)&xL[(r0 + 32*i)*KP + kq]);
#pragma unroll
      for (int kk = 0; kk < 4; kk++){
        float4 wa = *((const float4*)&wL[(kq+kk)*64 + cg]);
        float4 wb = *((const float4*)&wL[(kq+kk)*64 + cg + 4]);
#pragma unroll
        for (int i = 0; i < 4; i++){
          float xv = (kk==0)?xr[i].x:(kk==1)?xr[i].y:(kk==2)?xr[i].z:xr[i].w;
          acc[i][0] = fmaf(xv, wa.x, acc[i][0]);
          acc[i][1] = fmaf(xv, wa.y, acc[i][1]);
          acc[i][2] = fmaf(xv, wa.z, acc[i][2]);
          acc[i][3] = fmaf(xv, wa.w, acc[i][3]);
          acc[i][4] = fmaf(xv, wb.x, acc[i][4]);
          acc[i][5] = fmaf(xv, wb.y, acc[i][5]);
          acc[i][6] = fmaf(xv, wb.z, acc[i][6]);
          acc[i][7] = fmaf(xv, wb.w, acc[i][7]);
        }
      }
    }
  }
#pragma unroll
  for (int i = 0; i < 4; i++){
    int gr = rbase + r0 + 32*i;
    if (gr < NT){
      float4 oa = make_float4(acc[i][0], acc[i][1], acc[i][2], acc[i][3]);
      float4 ob = make_float4(acc[i][4], acc[i][5], acc[i][6], acc[i][7]);
      *((float4*)&H[(size_t)gr*64 + cg])     = oa;
      *((float4*)&H[(size_t)gr*64 + cg + 4]) = ob;
    }
  }
}

// ---------------- LDS-staged GCN aggregation ----------------
// One block per graph (256 blocks, 1 per CU), 1024 threads, two channel-half
// passes. Each pass: stage H[graph][32 ch] into LDS (stride 36 -> bank-
// conflict ~2-way = free per m136), then 8-lane groups gather each node's
// neighbors from LDS instead of L2 (eliminates ~200cy random-gather latency).
// DO_H4: fuse H4 = x3 @ W4 via per-pass partial dot in pdot[].
template<bool DO_H4>
__global__ __launch_bounds__(1024) void k_aggL(const float* __restrict__ H, const int* __restrict__ off,
                                               const int* __restrict__ srcs, const float* __restrict__ ws,
                                               const float* __restrict__ dis, const float* __restrict__ bias,
                                               const float* __restrict__ W4,
                                               float* __restrict__ Xout, float* __restrict__ H4,
                                               const int* __restrict__ gcount, const int* __restrict__ goff){
  __shared__ __align__(16) float hl[MAXN*HLP];   // 140.6 KB
  __shared__ float pdot[1024];                   // 4 KB (H4 partials)
  int g = blockIdx.x, tid = threadIdx.x;
  int n = gcount[g], base = goff[g];
  int l = tid & 7, gid = tid >> 3;               // 128 groups of 8 lanes
  int co = l*4;                                  // channel quad within half
#pragma unroll
  for (int pass = 0; pass < 2; pass++){
    int cbase = pass*32;
    if (pass == 1) __syncthreads();              // gather reads of pass 0 done
    // stage half-slice: coalesced float4 global reads
    for (int i = tid; i < n*8; i += 1024){
      int r = i >> 3, q = i & 7;
      *((float4*)&hl[r*HLP + q*4]) =
        *((const float4*)&H[(size_t)(base + r)*64 + cbase + q*4]);
    }
    __syncthreads();
    for (int v = gid; v < n; v += 128){
      int node = base + v;
      int s0 = off[node], s1 = off[node+1];
      float4 a0 = make_float4(0.f,0.f,0.f,0.f), a1 = a0, a2 = a0, a3 = a0;
      int e = s0;
      for (; e + 4 <= s1; e += 4){
        int   r0 = srcs[e]   - base, r1 = srcs[e+1] - base;
        int   r2 = srcs[e+2] - base, r3 = srcs[e+3] - base;
        float w0 = ws[e], w1 = ws[e+1], w2 = ws[e+2], w3 = ws[e+3];
        float4 h0 = *((const float4*)&hl[r0*HLP + co]);
        float4 h1 = *((const float4*)&hl[r1*HLP + co]);
        float4 h2 = *((const float4*)&hl[r2*HLP + co]);
        float4 h3 = *((const float4*)&hl[r3*HLP + co]);
        a0.x=fmaf(w0,h0.x,a0.x); a0.y=fmaf(w0,h0.y,a0.y); a0.z=fmaf(w0,h0.z,a0.z); a0.w=fmaf(w0,h0.w,a0.w);
        a1.x=fmaf(w1,h1.x,a1.x); a1.y=fmaf(w1,h1.y,a1.y); a1.z=fmaf(w1,h1.z,a1.z); a1.w=fmaf(w1,h1.w,a1.w);
        a2.x=fmaf(w2,h2.x,a2.x); a2.y=fmaf(w2,h2.y,a2.y); a2.z=fmaf(w2,h2.z,a2.z); a2.w=fmaf(w2,h2.w,a2.w);
        a3.x=fmaf(w3,h3.x,a3.x); a3.y=fmaf(w3,h3.y,a3.y); a3.z=fmaf(w3,h3.z,a3.z); a3.w=fmaf(w3,h3.w,a3.w);
      }
      for (; e < s1; e++){
        int r = srcs[e] - base; float w = ws[e];
        float4 h = *((const float4*)&hl[r*HLP + co]);
        a0.x=fmaf(w,h.x,a0.x); a0.y=fmaf(w,h.y,a0.y); a0.z=fmaf(w,h.z,a0.z); a0.w=fmaf(w,h.w,a0.w);
      }
      float4 acc;
      acc.x = (a0.x+a1.x)+(a2.x+a3.x);
      acc.y = (a0.y+a1.y)+(a2.y+a3.y);
      acc.z = (a0.z+a1.z)+(a2.z+a3.z);
      acc.w = (a0.w+a1.w)+(a2.w+a3.w);
      float dv = dis[node];
      float dv2 = dv*dv;
      float4 hs = *((const float4*)&hl[v*HLP + co]);
      float4 bb = *((const float4*)&bias[cbase + co]);
      float4 t;
      t.x = tanhf(acc.x + dv2*hs.x + bb.x);
      t.y = tanhf(acc.y + dv2*hs.y + bb.y);
      t.z = tanhf(acc.z + dv2*hs.z + bb.z);
      t.w = tanhf(acc.w + dv2*hs.w + bb.w);
      *((float4*)&Xout[(size_t)node*64 + cbase + co]) = t;
      if (DO_H4){
        float4 w4v = *((const float4*)&W4[cbase + co]);
        float p = t.x*w4v.x + t.y*w4v.y + t.z*w4v.z + t.w*w4v.w;
        p += __shfl_xor(p, 1);
        p += __shfl_xor(p, 2);
        p += __shfl_xor(p, 4);
        if (pass == 0){
          if (l == 0) pdot[v] = p;
        } else {
          if (l == 0) H4[node] = pdot[v] + p;
        }
      }
    }
  }
}

__global__ __launch_bounds__(256) void k_agg1(const float* __restrict__ H4, const int* __restrict__ off,
                                              const int* __restrict__ srcs, const float* __restrict__ ws,
                                              const float* __restrict__ dis, const float* __restrict__ b4,
                                              float* __restrict__ x4, int NT){
  int v = blockIdx.x*256 + threadIdx.x;
  if (v >= NT) return;
  int s0 = off[v], s1 = off[v+1];
  float acc = 0.f;
  for (int e = s0; e < s1; e++) acc = fmaf(ws[e], H4[srcs[e]], acc);
  float dv = dis[v];
  x4[v] = tanhf(acc + dv*dv*H4[v] + b4[0]);
}

// ---------------- fused stats: sqv + min + per-graph channel sums ----------
__global__ __launch_bounds__(256) void k_stats(const float* __restrict__ x1, const float* __restrict__ x2,
                                               const float* __restrict__ x3, const float* __restrict__ x4,
                                               const int* __restrict__ gcount, const int* __restrict__ goff,
                                               float* __restrict__ sqv, float* __restrict__ gpart,
                                               float* __restrict__ bmin){
  __shared__ float sm[256];
  __shared__ float wm[4];
  int g = blockIdx.x, p = blockIdx.y, tid = threadIdx.x;
  int wv = tid >> 6, lane = tid & 63;
  int n = gcount[g], base = goff[g];
  int n0 = (int)(((long long)n * p) / GPARTS);
  int n1 = (int)(((long long)n * (p+1)) / GPARTS);
  float a1 = 0.f, a2 = 0.f, a3 = 0.f;
  float a4 = 0.f, asq = 0.f;
  float mn = FLT_MAX;
  for (int i = n0 + wv; i < n1; i += 4){
    size_t node = (size_t)(base + i);
    float v1 = x1[node*64 + lane];
    float v2 = x2[node*64 + lane];
    float v3 = x3[node*64 + lane];
    a1 += v1; a2 += v2; a3 += v3;
    mn = fminf(mn, fminf(fminf(v1, v2), v3));
    float s = warp_sum64(v1*v1 + v2*v2 + v3*v3);
    if (lane == 0){
      float d = x4[node];
      float sq = s + d*d;
      sqv[node] = sq;
      a4 += d; asq += sq;
      mn = fminf(mn, d);
    }
  }
  float* out = &gpart[(size_t)(g*GPARTS + p) * 194];
  sm[tid] = a1; __syncthreads();
  if (tid < 64) out[tid] = sm[tid] + sm[tid+64] + sm[tid+128] + sm[tid+192];
  __syncthreads();
  sm[tid] = a2; __syncthreads();
  if (tid < 64) out[64 + tid] = sm[tid] + sm[tid+64] + sm[tid+128] + sm[tid+192];
  __syncthreads();
  sm[tid] = a3; __syncthreads();
  if (tid < 64) out[128 + tid] = sm[tid] + sm[tid+64] + sm[tid+128] + sm[tid+192];
  __syncthreads();
  sm[tid] = (lane == 0) ? a4 : 0.f; __syncthreads();
  for (int o = 128; o > 0; o >>= 1){
    if (tid < o) sm[tid] += sm[tid + o];
    __syncthreads();
  }
  if (tid == 0) out[192] = sm[0];
  __syncthreads();
  sm[tid] = (lane == 0) ? asq : 0.f; __syncthreads();
  for (int o = 128; o > 0; o >>= 1){
    if (tid < o) sm[tid] += sm[tid + o];
    __syncthreads();
  }
  if (tid == 0) out[193] = sm[0];
  mn = warp_min64(mn);
  if (lane == 0) wm[wv] = mn;
  __syncthreads();
  if (tid == 0)
    bmin[g*GPARTS + p] = fminf(fminf(wm[0], wm[1]), fminf(wm[2], wm[3]));
}
__global__ __launch_bounds__(256) void k_min2(const float* __restrict__ bmin, int nb, float* __restrict__ minv){
  __shared__ float sm[256];
  float m = FLT_MAX;
  for (int i = threadIdx.x; i < nb; i += 256) m = fminf(m, bmin[i]);
  sm[threadIdx.x] = m; __syncthreads();
  for (int o = 128; o > 0; o >>= 1){
    if (threadIdx.x < o) sm[threadIdx.x] = fminf(sm[threadIdx.x], sm[threadIdx.x + o]);
    __syncthreads();
  }
  if (threadIdx.x == 0) minv[0] = sm[0];
}
__global__ __launch_bounds__(256) void k_gcomb(const float* __restrict__ gpart, float* __restrict__ gstats){
  int g = blockIdx.x, c = threadIdx.x;
  if (c < 194){
    float s = 0.f;
    for (int p = 0; p < GPARTS; p++) s += gpart[(size_t)(g*GPARTS + p)*194 + c];
    gstats[g*194 + c] = s;
  }
}

// ---------------- per-graph sort of x4 (keys only) ----------------
__global__ __launch_bounds__(256) void k_sort(const float* __restrict__ x4, const int* __restrict__ gcount,
                                              const int* __restrict__ goff, int* __restrict__ sidxg,
                                              int* __restrict__ rank){
  __shared__ float sval[SORTN];
  __shared__ int   sidx[SORTN];
  int g = blockIdx.x, tid = threadIdx.x;
  int n = gcount[g], base = goff[g];
  for (int i = tid; i < SORTN; i += 256){
    sval[i] = (i < n) ? x4[base + i] : -FLT_MAX;
    sidx[i] = i;
  }
  __syncthreads();
  for (int k = 2; k <= SORTN; k <<= 1){
    for (int j = k >> 1; j > 0; j >>= 1){
      for (int t = tid; t < SORTN/2; t += 256){
        int i   = 2*t - (t & (j - 1));
        int ixj = i | j;
        bool up = ((i & k) == 0);
        float va = sval[i], vb = sval[ixj];
        int   ia = sidx[i], ib = sidx[ixj];
        bool aBeforeB = (va > vb) || (va == vb && ia < ib);
        bool bBeforeA = (vb > va) || (vb == va && ib < ia);
        bool doswap = up ? bBeforeA : aBeforeB;
        if (doswap){ sval[i] = vb; sval[ixj] = va; sidx[i] = ib; sidx[ixj] = ia; }
      }
      __syncthreads();
    }
  }
  for (int i = tid; i < SORTN; i += 256) sidxg[g*SORTN + i] = sidx[i];
  for (int i = tid; i < n; i += 256) rank[base + sidx[i]] = i;
}

// ---------------- per-graph: Srow/Tsum/sim_fill + x_sort gather ----------------
__global__ __launch_bounds__(256) void k_top27(const float* __restrict__ x1, const float* __restrict__ x2,
                                               const float* __restrict__ x3, const float* __restrict__ x4,
                                               const float* __restrict__ sqv, const int* __restrict__ gcount,
                                               const int* __restrict__ goff, const int* __restrict__ sidxg,
                                               const float* __restrict__ gstats, const float* __restrict__ minv,
                                               float* __restrict__ Srow, float* __restrict__ TS,
                                               float* __restrict__ pooled){
  __shared__ int   t27n[K2C];
  __shared__ float srow_s[DF];
  int g = blockIdx.x, tid = threadIdx.x;
  int n = gcount[g], base = goff[g];
  float fill = minv[0] - 1.0f;
  int nv = (n < NRESC) ? n : NRESC;
  int nreal = n - K2C;
  int nfill = nv - nreal;
  if (tid < K2C) t27n[tid] = base + sidxg[g*SORTN + tid];
  __syncthreads();
  if (tid < DF){
    float s = 0.f;
    for (int r = 0; r < K2C; r++) s += feat_at(x1, x2, x3, x4, t27n[r], tid);
    float v = gstats[g*194 + tid] - s + (float)nfill * fill;
    srow_s[tid] = v;
    Srow[g*DF + tid] = v;
  }
  for (int i = tid; i < K2C*DF; i += 256){
    int r = i / DF, d = i - r*DF;
    pooled[(size_t)g*PLEN + i] = feat_at(x1, x2, x3, x4, t27n[r], d);
  }
  __syncthreads();
  if (tid == 0){
    float t27sq = 0.f;
    for (int r = 0; r < K2C; r++) t27sq += sqv[t27n[r]];
    float sqfill = (float)DF * fill * fill;
    float Tsum = gstats[g*194 + 193] - t27sq + (float)nfill * sqfill;
    float ssum = 0.f;
    for (int d = 0; d < DF; d++) ssum += srow_s[d];
    float nf = (float)nv;
    float simfill = nf * sqfill + Tsum - 2.0f * fill * ssum;
    TS[g*2 + 0] = Tsum;
    TS[g*2 + 1] = simfill;
  }
}

// ---------------- per-node sim (coalesced) ----------------
__global__ __launch_bounds__(256) void k_sim(const float* __restrict__ x1, const float* __restrict__ x2,
                                             const float* __restrict__ x3, const float* __restrict__ x4,
                                             const float* __restrict__ sqv, const int* __restrict__ batch,
                                             const int* __restrict__ gcount, const int* __restrict__ rank,
                                             const float* __restrict__ Srow, const float* __restrict__ TS,
                                             float* __restrict__ sim, int NT){
  int wid  = blockIdx.x*4 + (threadIdx.x >> 6);
  int lane = threadIdx.x & 63;
  if (wid >= NT) return;
  if (rank[wid] < K2C) return;
  int g = batch[wid];
  float a = x1[(size_t)wid*64 + lane];
  float b = x2[(size_t)wid*64 + lane];
  float c = x3[(size_t)wid*64 + lane];
  float s1 = Srow[g*DF + lane];
  float s2 = Srow[g*DF + 64 + lane];
  float s3 = Srow[g*DF + 128 + lane];
  float dot = warp_sum64(a*s1 + b*s2 + c*s3);
  if (lane == 0){
    float d = x4[wid];
    dot += d * Srow[g*DF + 192];
    int n = gcount[g];
    float nf = (float)((n < NRESC) ? n : NRESC);
    sim[wid] = nf * sqv[wid] + TS[g*2] - 2.0f * dot;
  }
}

// ---------------- per-graph top-3 (parallel tree merge) + x_simi gather ----------------
DEV void top3_insert(float v, int j, float* tv, int* tj){
  if (v > tv[0] || (v == tv[0] && j < tj[0])){
    tv[2]=tv[1]; tj[2]=tj[1]; tv[1]=tv[0]; tj[1]=tj[0]; tv[0]=v; tj[0]=j;
  } else if (v > tv[1] || (v == tv[1] && j < tj[1])){
    tv[2]=tv[1]; tj[2]=tj[1]; tv[1]=v; tj[1]=j;
  } else if (v > tv[2] || (v == tv[2] && j < tj[2])){
    tv[2]=v; tj[2]=j;
  }
}
__global__ __launch_bounds__(256) void k_top3(const float* __restrict__ x1, const float* __restrict__ x2,
                                              const float* __restrict__ x3, const float* __restrict__ x4,
                                              const float* __restrict__ sim, const int* __restrict__ rank,
                                              const int* __restrict__ gcount, const int* __restrict__ goff,
                                              const int* __restrict__ sidxg, const float* __restrict__ TS,
                                              const float* __restrict__ minv, float* __restrict__ pooled){
  __shared__ float lv[256*3];
  __shared__ int   lj[256*3];
  __shared__ int   fsel[3];
  int g = blockIdx.x, tid = threadIdx.x;
  int n = gcount[g], base = goff[g];
  float fill = minv[0] - 1.0f;
  int nv = (n < NRESC) ? n : NRESC;
  int nreal = n - K2C;
  int nfill = nv - nreal;
  float tv[3] = {-FLT_MAX, -FLT_MAX, -FLT_MAX};
  int   tj[3] = {INT_MAX, INT_MAX, INT_MAX};
  for (int i = tid; i < n; i += 256){
    int node = base + i;
    int r = rank[node];
    if (r >= K2C) top3_insert(sim[node], r - K2C, tv, tj);
  }
#pragma unroll
  for (int q = 0; q < 3; q++){ lv[tid*3 + q] = tv[q]; lj[tid*3 + q] = tj[q]; }
  __syncthreads();
  for (int o = 128; o >= 1; o >>= 1){
    if (tid < o){
#pragma unroll
      for (int q = 0; q < 3; q++)
        top3_insert(lv[(tid + o)*3 + q], lj[(tid + o)*3 + q], tv, tj);
#pragma unroll
      for (int q = 0; q < 3; q++){ lv[tid*3 + q] = tv[q]; lj[tid*3 + q] = tj[q]; }
    }
    __syncthreads();
  }
  if (tid == 0){
    float simfill = TS[g*2 + 1];
    int ninj = (nfill < 3) ? nfill : 3;
    for (int q = 0; q < ninj; q++) top3_insert(simfill, nreal + q, tv, tj);
    fsel[0] = tj[0]; fsel[1] = tj[1]; fsel[2] = tj[2];
  }
  __syncthreads();
  for (int i = tid; i < K1C*DF; i += 256){
    int m = i / DF, d = i - m*DF;
    int j = fsel[m];
    float v;
    if (j < nreal){
      int node = base + sidxg[g*SORTN + K2C + j];
      v = feat_at(x1, x2, x3, x4, node, d);
    } else {
      v = fill;
    }
    pooled[(size_t)g*PLEN + K2C*DF + i] = v;
  }
}

// ---------------- conv5 + pairmax + conv6 (LDS-transposed weights, ILP4) ----
__global__ __launch_bounds__(256) void k_head(const float* __restrict__ pooled, const float* __restrict__ w5,
                                              const float* __restrict__ b5, const float* __restrict__ w6,
                                              const float* __restrict__ b6, float* __restrict__ h6){
  __shared__ float smem[21760];               // 87 KB
  float* pl  = smem;
  float* w5T = smem + 5790;
  float* h5  = smem + 18528;
  float* mx  = smem;
  float* w6T = smem + 960;
  int g = blockIdx.x, tid = threadIdx.x;
  for (int i = tid; i < PLEN; i += 256) pl[i] = pooled[(size_t)g*PLEN + i];
  for (int i = tid; i < 64*DF; i += 256){
    int o = i / DF, d = i - o*DF;
    w5T[d*66 + o] = w5[i];
  }
  __syncthreads();
  int o = tid & 63, tg = tid >> 6;
  for (int t = tg; t < 30; t += 4){
    const float* pr = &pl[t*DF];
    float a0=0.f, a1=0.f, a2=0.f, a3=0.f;
    for (int d = 0; d < 192; d += 4){
      a0 = fmaf(pr[d],   w5T[(d)*66 + o],   a0);
      a1 = fmaf(pr[d+1], w5T[(d+1)*66 + o], a1);
      a2 = fmaf(pr[d+2], w5T[(d+2)*66 + o], a2);
      a3 = fmaf(pr[d+3], w5T[(d+3)*66 + o], a3);
    }
    a0 = fmaf(pr[192], w5T[192*66 + o], a0);
    float acc = b5[o] + ((a0 + a1) + (a2 + a3));
    h5[t*64 + o] = fmaxf(acc, 0.f);
  }
  __syncthreads();
  for (int i = tid; i < 15*64; i += 256){
    int p = i >> 6, oo = i & 63;
    mx[i] = fmaxf(h5[(2*p)*64 + oo], h5[(2*p + 1)*64 + oo]);
  }
  __syncthreads();
  for (int i = tid; i < 64*64*5; i += 256){
    int oo = i / 320, rem = i - oo*320;
    w6T[rem*65 + oo] = w6[i];
  }
  __syncthreads();
  for (int t = tg; t < 11; t += 4){
    float a0=0.f, a1=0.f, a2=0.f, a3=0.f;
    for (int ii = 0; ii < 64; ii += 4){
#pragma unroll
      for (int k = 0; k < 5; k++){
        a0 = fmaf(mx[(t+k)*64 + ii],   w6T[((ii)*5   + k)*65 + o], a0);
        a1 = fmaf(mx[(t+k)*64 + ii+1], w6T[((ii+1)*5 + k)*65 + o], a1);
        a2 = fmaf(mx[(t+k)*64 + ii+2], w6T[((ii+2)*5 + k)*65 + o], a2);
        a3 = fmaf(mx[(t+k)*64 + ii+3], w6T[((ii+3)*5 + k)*65 + o], a3);
      }
    }
    float acc = b6[o] + ((a0 + a1) + (a2 + a3));
    h6[(size_t)g*704 + o*11 + t] = fmaxf(acc, 0.f);
  }
}

// ---------------- FC: 256 x 704 @ 704 x 1600, ReLU ----------------
__global__ __launch_bounds__(256) void k_fc(const float* __restrict__ h6, const float* __restrict__ fw,
                                            const float* __restrict__ fb, float* __restrict__ out){
  int j  = blockIdx.x*64 + (threadIdx.x & 63);
  int b0 = __builtin_amdgcn_readfirstlane(blockIdx.y*16 + (threadIdx.x >> 6)*4);
  const float* h0p = h6 + (size_t)b0*704;
  const float* h1p = h0p + 704;
  const float* h2p = h0p + 1408;
  const float* h3p = h0p + 2112;
  float a0e=0.f,a0o=0.f,a1e=0.f,a1o=0.f,a2e=0.f,a2o=0.f,a3e=0.f,a3o=0.f;
#pragma unroll 4
  for (int k = 0; k < 704; k += 2){
    float w0 = fw[(size_t)k*1600 + j];
    float w1 = fw[(size_t)k*1600 + 1600 + j];
    a0e = fmaf(h0p[k], w0, a0e); a0o = fmaf(h0p[k+1], w1, a0o);
    a1e = fmaf(h1p[k], w0, a1e); a1o = fmaf(h1p[k+1], w1, a1o);
    a2e = fmaf(h2p[k], w0, a2e); a2o = fmaf(h2p[k+1], w1, a2o);
    a3e = fmaf(h3p[k], w0, a3e); a3o = fmaf(h3p[k+1], w1, a3o);
  }
  float fbj = fb[j];
  out[(size_t)b0*1600 + j]       = fmaxf(a0e + a0o + fbj, 0.f);
  out[(size_t)(b0+1)*1600 + j]   = fmaxf(a1e + a1o + fbj, 0.f);
  out[(size_t)(b0+2)*1600 + j]   = fmaxf(a2e + a2o + fbj, 0.f);
  out[(size_t)(b0+3)*1600 + j]   = fmaxf(a3e + a3o + fbj, 0.f);
}

extern "C" void kernel_launch(void* const* d_in, const int* in_sizes, int n_in,
                              void* d_out, int out_size, void* d_ws, size_t ws_size,
                              hipStream_t stream){
  const float* x    = (const float*)d_in[0];
  const int*   ei   = (const int*)d_in[1];
  const int*   batch= (const int*)d_in[2];
  const float* W1 = (const float*)d_in[3];  const float* b1 = (const float*)d_in[4];
  const float* W2 = (const float*)d_in[5];  const float* b2 = (const float*)d_in[6];
  const float* W3 = (const float*)d_in[7];  const float* b3 = (const float*)d_in[8];
  const float* W4 = (const float*)d_in[9];  const float* b4 = (const float*)d_in[10];
  const float* w5 = (const float*)d_in[11]; const float* b5 = (const float*)d_in[12];
  const float* w6 = (const float*)d_in[13]; const float* b6 = (const float*)d_in[14];
  const float* fw = (const float*)d_in[15]; const float* fb = (const float*)d_in[16];
  float* out = (float*)d_out;

  const int NT = in_sizes[2];
  const int E  = in_sizes[1] / 2;
  const int epg = E / BG;
  const int* rows = ei;
  const int* cols = ei + E;

  char* ws = (char*)d_ws;
  size_t off = 0;
  auto alloc = [&](size_t bytes) -> char* {
    off = (off + 255) & ~(size_t)255;
    char* p = ws + off;
    off += bytes;
    return p;
  };

  int*      gcount  = (int*)     alloc(BG * 4);
  int*      goff    = (int*)     alloc((BG + 1) * 4);
  float*    minv    = (float*)   alloc(4);
  float*    bmin    = (float*)   alloc((size_t)BG * GPARTS * 4);
  float*    dis     = (float*)   alloc((size_t)NT * 4);
  int*      csr_off = (int*)     alloc((size_t)(NT + 1) * 4);
  int*      csr_src = (int*)     alloc((size_t)E * 4);
  float*    csr_w   = (float*)   alloc((size_t)E * 4);
  float*    HbufA   = (float*)   alloc((size_t)NT * 64 * 4);
  float*    HbufB   = (float*)   alloc((size_t)NT * 64 * 4);
  float*    x1      = (float*)   alloc((size_t)NT * 64 * 4);
  float*    x2      = (float*)   alloc((size_t)NT * 64 * 4);
  float*    x3      = (float*)   alloc((size_t)NT * 64 * 4);
  float*    x4      = (float*)   alloc((size_t)NT * 4);
  float*    H4      = (float*)   alloc((size_t)NT * 4);
  float*    sqv     = (float*)   alloc((size_t)NT * 4);
  float*    simv    = (float*)   alloc((size_t)NT * 4);
  int*      rank    = (int*)     alloc((size_t)NT * 4);
  int*      sidxg   = (int*)     alloc((size_t)BG * SORTN * 4);
  float*    gpart   = (float*)   alloc((size_t)BG * GPARTS * 194 * 4);
  float*    gstats  = (float*)   alloc((size_t)BG * 194 * 4);
  float*    Srow    = (float*)   alloc((size_t)BG * DF * 4);
  float*    TS      = (float*)   alloc((size_t)BG * 2 * 4);
  float*    pooled  = (float*)   alloc((size_t)BG * PLEN * 4);
  float*    h6      = (float*)   alloc((size_t)BG * 704 * 4);

  const int gridNT = (NT + 255) / 256;
  const int gridS  = (NT + 3) / 4;        // wave-per-node (k_sim)
  const int gridG  = (NT + 127) / 128;    // 128-row GEMM tiles

  k_bounds<<<gridNT, 256, 0, stream>>>(batch, goff, NT);
  k_gcount<<<1, 256, 0, stream>>>(goff, gcount);
  k_build<<<BG, 1024, 0, stream>>>(rows, cols, gcount, goff, dis, csr_off, csr_src, csr_w, NT, E, epg);

  // all layers: low-register GEMM (8 waves/SIMD target) + LDS-staged agg
  k_gemm_lo<128><<<gridG, 256, 0, stream>>>(x, W1, HbufA, NT);
  k_aggL<false><<<BG, 1024, 0, stream>>>(HbufA, csr_off, csr_src, csr_w, dis, b1, W4, x1, H4, gcount, goff);
  k_gemm_lo<64><<<gridG, 256, 0, stream>>>(x1, W2, HbufB, NT);
  k_aggL<false><<<BG, 1024, 0, stream>>>(HbufB, csr_off, csr_src, csr_w, dis, b2, W4, x2, H4, gcount, goff);
  k_gemm_lo<64><<<gridG, 256, 0, stream>>>(x2, W3, HbufA, NT);
  k_aggL<true><<<BG, 1024, 0, stream>>>(HbufA, csr_off, csr_src, csr_w, dis, b3, W4, x3, H4, gcount, goff);
  k_agg1<<<gridNT, 256, 0, stream>>>(H4, csr_off, csr_src, csr_w, dis, b4, x4, NT);

  k_stats<<<dim3(BG, GPARTS), 256, 0, stream>>>(x1, x2, x3, x4, gcount, goff, sqv, gpart, bmin);
  k_min2<<<1, 256, 0, stream>>>(bmin, BG*GPARTS, minv);
  k_gcomb<<<BG, 256, 0, stream>>>(gpart, gstats);
  k_sort<<<BG, 256, 0, stream>>>(x4, gcount, goff, sidxg, rank);
  k_top27<<<BG, 256, 0, stream>>>(x1, x2, x3, x4, sqv, gcount, goff, sidxg, gstats, minv, Srow, TS, pooled);
  k_sim<<<gridS, 256, 0, stream>>>(x1, x2, x3, x4, sqv, batch, gcount, rank, Srow, TS, simv, NT);
  k_top3<<<BG, 256, 0, stream>>>(x1, x2, x3, x4, simv, rank, gcount, goff, sidxg, TS, minv, pooled);

  k_head<<<BG, 256, 0, stream>>>(pooled, w5, b5, w6, b6, h6);
  k_fc<<<dim3(25, 16), 256, 0, stream>>>(h6, fw, fb, out);
}

// Round 28
// 613.685 us; speedup vs baseline: 1.0128x; 1.0128x over previous
//
#include <hip/hip_runtime.h>
#include <float.h>
#include <limits.h>

// Problem constants (fixed by setup_inputs)
static const int BG    = 256;    // graphs
static const int SORTN = 1024;   // bitonic size >= MAXN=1000
static const int DF    = 193;    // 64+64+64+1
static const int K2C   = 27;
static const int K1C   = 3;
static const int NRESC = 973;    // MAXN - K2
static const int PLEN  = 5790;   // 30*193
static const int GPARTS= 8;      // stats split factor
static const int MAXE  = 8192;   // LDS edge capacity >= EPG=7813
static const int MAXN  = 1000;   // max nodes per graph
static const int HLP   = 36;     // LDS half-slice row stride (32 + 4 pad, 16B-aligned)

#define DEV static __device__ __forceinline__

DEV float warp_sum64(float v){
#pragma unroll
  for (int o = 1; o < 64; o <<= 1) v += __shfl_xor(v, o);
  return v;
}
DEV float warp_min64(float v){
#pragma unroll
  for (int o = 1; o < 64; o <<= 1) v = fminf(v, __shfl_xor(v, o));
  return v;
}
DEV float feat_at(const float* __restrict__ x1, const float* __restrict__ x2,
                  const float* __restrict__ x3, const float* __restrict__ x4,
                  int node, int d){
  if (d < 64)  return x1[node*64 + d];
  if (d < 128) return x2[node*64 + (d-64)];
  if (d < 192) return x3[node*64 + (d-128)];
  return x4[node];
}

// ---------------- graph prep ----------------
__global__ __launch_bounds__(256) void k_bounds(const int* __restrict__ batch, int* __restrict__ goff, int NT){
  int i = blockIdx.x*256 + threadIdx.x;
  if (i < NT){
    if (i == 0 || batch[i] != batch[i-1]) goff[batch[i]] = i;
    if (i == NT-1) goff[BG] = NT;
  }
}
__global__ void k_gcount(const int* __restrict__ goff, int* __restrict__ gcount){
  int g = blockIdx.x*256 + threadIdx.x;
  if (g < BG) gcount[g] = goff[g+1] - goff[g];
}

// One block per graph, 1024 threads. Degree count + dis + csr_off + LDS
// scatter + per-node sort + coalesced write-out. All atomics LDS-scope.
__global__ __launch_bounds__(1024) void k_build(const int* __restrict__ rows, const int* __restrict__ cols,
                                                const int* __restrict__ gcount, const int* __restrict__ goff,
                                                float* __restrict__ dis, int* __restrict__ csr_off,
                                                int* __restrict__ csr_src, float* __restrict__ csr_w,
                                                int NT, int E, int epg){
  __shared__ int   lsrc[MAXE];
  __shared__ float lw[MAXE];
  __shared__ int   cnt[1024];
  __shared__ int   offl[1024];
  __shared__ int   cur[1024];
  __shared__ float disl[1024];
  __shared__ int   sm[1024];
  int g = blockIdx.x, tid = threadIdx.x;
  int n = gcount[g], base = goff[g];
  int ebase = g*epg;
  cnt[tid] = 0;
  __syncthreads();
  for (int i = tid; i < epg; i += 1024)
    atomicAdd(&cnt[cols[ebase+i] - base], 1);
  __syncthreads();
  if (tid < n){
    float d = 1.0f / sqrtf((float)cnt[tid] + 1.0f);
    disl[tid] = d;
    dis[base + tid] = d;
  }
  sm[tid] = cnt[tid]; __syncthreads();
  for (int o = 1; o < 1024; o <<= 1){
    int add = (tid >= o) ? sm[tid - o] : 0;
    __syncthreads(); sm[tid] += add; __syncthreads();
  }
  int excl = (tid > 0) ? sm[tid - 1] : 0;
  offl[tid] = excl; cur[tid] = excl;
  __syncthreads();
  if (tid < n) csr_off[base + tid] = ebase + offl[tid];
  if (g == BG - 1 && tid == 0) csr_off[NT] = E;
  for (int i = tid; i < epg; i += 1024){
    int r = rows[ebase + i], c = cols[ebase + i];
    float w = disl[r - base] * disl[c - base];
    int pos = atomicAdd(&cur[c - base], 1);
    lsrc[pos] = r;
    lw[pos]   = w;
  }
  __syncthreads();
  if (tid < n){
    int s0 = offl[tid];
    int s1 = (tid + 1 < n) ? offl[tid + 1] : epg;
    for (int i = s0 + 1; i < s1; i++){
      int ks = lsrc[i]; float kw = lw[i];
      int j = i - 1;
      while (j >= s0 && lsrc[j] > ks){ lsrc[j+1] = lsrc[j]; lw[j+1] = lw[j]; j--; }
      lsrc[j+1] = ks; lw[j+1] = kw;
    }
  }
  __syncthreads();
  for (int i = tid; i < epg; i += 1024){
    csr_src[ebase + i] = lsrc[i];
    csr_w[ebase + i]   = lw[i];
  }
}

// ---------------- low-register GEMM: BK=64 single/double stage -------------
// K=64: ONE stage (12 back-to-back global float4 loads/thread -> deep MLP),
// one barrier, then pure LDS compute. K=128: two such phases. Ascending-k
// accumulation, identical fmaf sequence -> bit-identical H. LDS 50 KB ->
// 3 blocks/CU. xL row stride 68 -> 8 rows span 8 distinct banks.
template<int K>
__global__ __launch_bounds__(256, 4) void k_gemm_lo(const float* __restrict__ X, const float* __restrict__ W,
                                                    float* __restrict__ H, int NT){
  const int BK = 64, KP = 68, NC = K/BK, TR = 128;
  __shared__ __align__(16) float xL[TR*KP];   // 34816 B
  __shared__ __align__(16) float wL[BK*64];   // 16384 B
  int tid = threadIdx.x;
  int rbase = blockIdx.x * TR;
  int r0 = tid >> 3;
  int cg = (tid & 7) * 8;
  float acc[4][8];
#pragma unroll
  for (int i = 0; i < 4; i++)
#pragma unroll
    for (int j = 0; j < 8; j++) acc[i][j] = 0.f;
  for (int c = 0; c < NC; c++){
    int k0 = c*BK;
    if (c > 0) __syncthreads();
    // stage X chunk: 128 rows x 16 float4 = 2048 -> 8 per thread
#pragma unroll
    for (int q = 0; q < 8; q++){
      int p = q*256 + tid;
      int row = p >> 4, c4 = p & 15;
      int gr = rbase + row;
      float4 v = make_float4(0.f,0.f,0.f,0.f);
      if (gr < NT) v = *((const float4*)&X[(size_t)gr*K + k0 + c4*4]);
      *((float4*)&xL[row*KP + c4*4]) = v;
    }
    // stage W chunk: 64 rows x 16 float4 = 1024 -> 4 per thread
#pragma unroll
    for (int j = 0; j < 4; j++){
      int i = j*256 + tid;
      int kr = i >> 4, cc = (i & 15)*4;
      float4 v = *((const float4*)&W[(size_t)(k0 + kr)*64 + cc]);
      *((float4*)&wL[kr*64 + cc]) = v;
    }
    __syncthreads();
    for (int kq = 0; kq < BK; kq += 4){
      float4 xr[4];
#pragma unroll
      for (int i = 0; i < 4; i++) xr[i] = *((const float4*)&xL[(r0 + 32*i)*KP + kq]);
#pragma unroll
      for (int kk = 0; kk < 4; kk++){
        float4 wa = *((const float4*)&wL[(kq+kk)*64 + cg]);
        float4 wb = *((const float4*)&wL[(kq+kk)*64 + cg + 4]);
#pragma unroll
        for (int i = 0; i < 4; i++){
          float xv = (kk==0)?xr[i].x:(kk==1)?xr[i].y:(kk==2)?xr[i].z:xr[i].w;
          acc[i][0] = fmaf(xv, wa.x, acc[i][0]);
          acc[i][1] = fmaf(xv, wa.y, acc[i][1]);
          acc[i][2] = fmaf(xv, wa.z, acc[i][2]);
          acc[i][3] = fmaf(xv, wa.w, acc[i][3]);
          acc[i][4] = fmaf(xv, wb.x, acc[i][4]);
          acc[i][5] = fmaf(xv, wb.y, acc[i][5]);
          acc[i][6] = fmaf(xv, wb.z, acc[i][6]);
          acc[i][7] = fmaf(xv, wb.w, acc[i][7]);
        }
      }
    }
  }
#pragma unroll
  for (int i = 0; i < 4; i++){
    int gr = rbase + r0 + 32*i;
    if (gr < NT){
      float4 oa = make_float4(acc[i][0], acc[i][1], acc[i][2], acc[i][3]);
      float4 ob = make_float4(acc[i][4], acc[i][5], acc[i][6], acc[i][7]);
      *((float4*)&H[(size_t)gr*64 + cg])     = oa;
      *((float4*)&H[(size_t)gr*64 + cg + 4]) = ob;
    }
  }
}

// ---------------- LDS-staged GCN aggregation ----------------
// One block per graph (256 blocks, 1 per CU), 1024 threads, two channel-half
// passes. Each pass: stage H[graph][32 ch] into LDS (stride 36 -> bank-
// conflict ~2-way = free per m136), then 8-lane groups gather each node's
// neighbors from LDS instead of L2 (eliminates ~200cy random-gather latency).
// DO_H4: fuse H4 = x3 @ W4 via per-pass partial dot in pdot[].
template<bool DO_H4>
__global__ __launch_bounds__(1024) void k_aggL(const float* __restrict__ H, const int* __restrict__ off,
                                               const int* __restrict__ srcs, const float* __restrict__ ws,
                                               const float* __restrict__ dis, const float* __restrict__ bias,
                                               const float* __restrict__ W4,
                                               float* __restrict__ Xout, float* __restrict__ H4,
                                               const int* __restrict__ gcount, const int* __restrict__ goff){
  __shared__ __align__(16) float hl[MAXN*HLP];   // 140.6 KB
  __shared__ float pdot[1024];                   // 4 KB (H4 partials)
  int g = blockIdx.x, tid = threadIdx.x;
  int n = gcount[g], base = goff[g];
  int l = tid & 7, gid = tid >> 3;               // 128 groups of 8 lanes
  int co = l*4;                                  // channel quad within half
#pragma unroll
  for (int pass = 0; pass < 2; pass++){
    int cbase = pass*32;
    if (pass == 1) __syncthreads();              // gather reads of pass 0 done
    // stage half-slice: coalesced float4 global reads
    for (int i = tid; i < n*8; i += 1024){
      int r = i >> 3, q = i & 7;
      *((float4*)&hl[r*HLP + q*4]) =
        *((const float4*)&H[(size_t)(base + r)*64 + cbase + q*4]);
    }
    __syncthreads();
    for (int v = gid; v < n; v += 128){
      int node = base + v;
      int s0 = off[node], s1 = off[node+1];
      float4 a0 = make_float4(0.f,0.f,0.f,0.f), a1 = a0, a2 = a0, a3 = a0;
      int e = s0;
      for (; e + 4 <= s1; e += 4){
        int   r0 = srcs[e]   - base, r1 = srcs[e+1] - base;
        int   r2 = srcs[e+2] - base, r3 = srcs[e+3] - base;
        float w0 = ws[e], w1 = ws[e+1], w2 = ws[e+2], w3 = ws[e+3];
        float4 h0 = *((const float4*)&hl[r0*HLP + co]);
        float4 h1 = *((const float4*)&hl[r1*HLP + co]);
        float4 h2 = *((const float4*)&hl[r2*HLP + co]);
        float4 h3 = *((const float4*)&hl[r3*HLP + co]);
        a0.x=fmaf(w0,h0.x,a0.x); a0.y=fmaf(w0,h0.y,a0.y); a0.z=fmaf(w0,h0.z,a0.z); a0.w=fmaf(w0,h0.w,a0.w);
        a1.x=fmaf(w1,h1.x,a1.x); a1.y=fmaf(w1,h1.y,a1.y); a1.z=fmaf(w1,h1.z,a1.z); a1.w=fmaf(w1,h1.w,a1.w);
        a2.x=fmaf(w2,h2.x,a2.x); a2.y=fmaf(w2,h2.y,a2.y); a2.z=fmaf(w2,h2.z,a2.z); a2.w=fmaf(w2,h2.w,a2.w);
        a3.x=fmaf(w3,h3.x,a3.x); a3.y=fmaf(w3,h3.y,a3.y); a3.z=fmaf(w3,h3.z,a3.z); a3.w=fmaf(w3,h3.w,a3.w);
      }
      for (; e < s1; e++){
        int r = srcs[e] - base; float w = ws[e];
        float4 h = *((const float4*)&hl[r*HLP + co]);
        a0.x=fmaf(w,h.x,a0.x); a0.y=fmaf(w,h.y,a0.y); a0.z=fmaf(w,h.z,a0.z); a0.w=fmaf(w,h.w,a0.w);
      }
      float4 acc;
      acc.x = (a0.x+a1.x)+(a2.x+a3.x);
      acc.y = (a0.y+a1.y)+(a2.y+a3.y);
      acc.z = (a0.z+a1.z)+(a2.z+a3.z);
      acc.w = (a0.w+a1.w)+(a2.w+a3.w);
      float dv = dis[node];
      float dv2 = dv*dv;
      float4 hs = *((const float4*)&hl[v*HLP + co]);
      float4 bb = *((const float4*)&bias[cbase + co]);
      float4 t;
      t.x = tanhf(acc.x + dv2*hs.x + bb.x);
      t.y = tanhf(acc.y + dv2*hs.y + bb.y);
      t.z = tanhf(acc.z + dv2*hs.z + bb.z);
      t.w = tanhf(acc.w + dv2*hs.w + bb.w);
      *((float4*)&Xout[(size_t)node*64 + cbase + co]) = t;
      if (DO_H4){
        float4 w4v = *((const float4*)&W4[cbase + co]);
        float p = t.x*w4v.x + t.y*w4v.y + t.z*w4v.z + t.w*w4v.w;
        p += __shfl_xor(p, 1);
        p += __shfl_xor(p, 2);
        p += __shfl_xor(p, 4);
        if (pass == 0){
          if (l == 0) pdot[v] = p;
        } else {
          if (l == 0) H4[node] = pdot[v] + p;
        }
      }
    }
  }
}

__global__ __launch_bounds__(256) void k_agg1(const float* __restrict__ H4, const int* __restrict__ off,
                                              const int* __restrict__ srcs, const float* __restrict__ ws,
                                              const float* __restrict__ dis, const float* __restrict__ b4,
                                              float* __restrict__ x4, int NT){
  int v = blockIdx.x*256 + threadIdx.x;
  if (v >= NT) return;
  int s0 = off[v], s1 = off[v+1];
  float acc = 0.f;
  for (int e = s0; e < s1; e++) acc = fmaf(ws[e], H4[srcs[e]], acc);
  float dv = dis[v];
  x4[v] = tanhf(acc + dv*dv*H4[v] + b4[0]);
}

// ---------------- fused stats: sqv + min + per-graph channel sums ----------
__global__ __launch_bounds__(256) void k_stats(const float* __restrict__ x1, const float* __restrict__ x2,
                                               const float* __restrict__ x3, const float* __restrict__ x4,
                                               const int* __restrict__ gcount, const int* __restrict__ goff,
                                               float* __restrict__ sqv, float* __restrict__ gpart,
                                               float* __restrict__ bmin){
  __shared__ float sm[256];
  __shared__ float wm[4];
  int g = blockIdx.x, p = blockIdx.y, tid = threadIdx.x;
  int wv = tid >> 6, lane = tid & 63;
  int n = gcount[g], base = goff[g];
  int n0 = (int)(((long long)n * p) / GPARTS);
  int n1 = (int)(((long long)n * (p+1)) / GPARTS);
  float a1 = 0.f, a2 = 0.f, a3 = 0.f;
  float a4 = 0.f, asq = 0.f;
  float mn = FLT_MAX;
  for (int i = n0 + wv; i < n1; i += 4){
    size_t node = (size_t)(base + i);
    float v1 = x1[node*64 + lane];
    float v2 = x2[node*64 + lane];
    float v3 = x3[node*64 + lane];
    a1 += v1; a2 += v2; a3 += v3;
    mn = fminf(mn, fminf(fminf(v1, v2), v3));
    float s = warp_sum64(v1*v1 + v2*v2 + v3*v3);
    if (lane == 0){
      float d = x4[node];
      float sq = s + d*d;
      sqv[node] = sq;
      a4 += d; asq += sq;
      mn = fminf(mn, d);
    }
  }
  float* out = &gpart[(size_t)(g*GPARTS + p) * 194];
  sm[tid] = a1; __syncthreads();
  if (tid < 64) out[tid] = sm[tid] + sm[tid+64] + sm[tid+128] + sm[tid+192];
  __syncthreads();
  sm[tid] = a2; __syncthreads();
  if (tid < 64) out[64 + tid] = sm[tid] + sm[tid+64] + sm[tid+128] + sm[tid+192];
  __syncthreads();
  sm[tid] = a3; __syncthreads();
  if (tid < 64) out[128 + tid] = sm[tid] + sm[tid+64] + sm[tid+128] + sm[tid+192];
  __syncthreads();
  sm[tid] = (lane == 0) ? a4 : 0.f; __syncthreads();
  for (int o = 128; o > 0; o >>= 1){
    if (tid < o) sm[tid] += sm[tid + o];
    __syncthreads();
  }
  if (tid == 0) out[192] = sm[0];
  __syncthreads();
  sm[tid] = (lane == 0) ? asq : 0.f; __syncthreads();
  for (int o = 128; o > 0; o >>= 1){
    if (tid < o) sm[tid] += sm[tid + o];
    __syncthreads();
  }
  if (tid == 0) out[193] = sm[0];
  mn = warp_min64(mn);
  if (lane == 0) wm[wv] = mn;
  __syncthreads();
  if (tid == 0)
    bmin[g*GPARTS + p] = fminf(fminf(wm[0], wm[1]), fminf(wm[2], wm[3]));
}
__global__ __launch_bounds__(256) void k_min2(const float* __restrict__ bmin, int nb, float* __restrict__ minv){
  __shared__ float sm[256];
  float m = FLT_MAX;
  for (int i = threadIdx.x; i < nb; i += 256) m = fminf(m, bmin[i]);
  sm[threadIdx.x] = m; __syncthreads();
  for (int o = 128; o > 0; o >>= 1){
    if (threadIdx.x < o) sm[threadIdx.x] = fminf(sm[threadIdx.x], sm[threadIdx.x + o]);
    __syncthreads();
  }
  if (threadIdx.x == 0) minv[0] = sm[0];
}
__global__ __launch_bounds__(256) void k_gcomb(const float* __restrict__ gpart, float* __restrict__ gstats){
  int g = blockIdx.x, c = threadIdx.x;
  if (c < 194){
    float s = 0.f;
    for (int p = 0; p < GPARTS; p++) s += gpart[(size_t)(g*GPARTS + p)*194 + c];
    gstats[g*194 + c] = s;
  }
}

// ---------------- per-graph sort of x4 (keys only) ----------------
__global__ __launch_bounds__(256) void k_sort(const float* __restrict__ x4, const int* __restrict__ gcount,
                                              const int* __restrict__ goff, int* __restrict__ sidxg,
                                              int* __restrict__ rank){
  __shared__ float sval[SORTN];
  __shared__ int   sidx[SORTN];
  int g = blockIdx.x, tid = threadIdx.x;
  int n = gcount[g], base = goff[g];
  for (int i = tid; i < SORTN; i += 256){
    sval[i] = (i < n) ? x4[base + i] : -FLT_MAX;
    sidx[i] = i;
  }
  __syncthreads();
  for (int k = 2; k <= SORTN; k <<= 1){
    for (int j = k >> 1; j > 0; j >>= 1){
      for (int t = tid; t < SORTN/2; t += 256){
        int i   = 2*t - (t & (j - 1));
        int ixj = i | j;
        bool up = ((i & k) == 0);
        float va = sval[i], vb = sval[ixj];
        int   ia = sidx[i], ib = sidx[ixj];
        bool aBeforeB = (va > vb) || (va == vb && ia < ib);
        bool bBeforeA = (vb > va) || (vb == va && ib < ia);
        bool doswap = up ? bBeforeA : aBeforeB;
        if (doswap){ sval[i] = vb; sval[ixj] = va; sidx[i] = ib; sidx[ixj] = ia; }
      }
      __syncthreads();
    }
  }
  for (int i = tid; i < SORTN; i += 256) sidxg[g*SORTN + i] = sidx[i];
  for (int i = tid; i < n; i += 256) rank[base + sidx[i]] = i;
}

// ---------------- per-graph: Srow/Tsum/sim_fill + x_sort gather ----------------
__global__ __launch_bounds__(256) void k_top27(const float* __restrict__ x1, const float* __restrict__ x2,
                                               const float* __restrict__ x3, const float* __restrict__ x4,
                                               const float* __restrict__ sqv, const int* __restrict__ gcount,
                                               const int* __restrict__ goff, const int* __restrict__ sidxg,
                                               const float* __restrict__ gstats, const float* __restrict__ minv,
                                               float* __restrict__ Srow, float* __restrict__ TS,
                                               float* __restrict__ pooled){
  __shared__ int   t27n[K2C];
  __shared__ float srow_s[DF];
  int g = blockIdx.x, tid = threadIdx.x;
  int n = gcount[g], base = goff[g];
  float fill = minv[0] - 1.0f;
  int nv = (n < NRESC) ? n : NRESC;
  int nreal = n - K2C;
  int nfill = nv - nreal;
  if (tid < K2C) t27n[tid] = base + sidxg[g*SORTN + tid];
  __syncthreads();
  if (tid < DF){
    float s = 0.f;
    for (int r = 0; r < K2C; r++) s += feat_at(x1, x2, x3, x4, t27n[r], tid);
    float v = gstats[g*194 + tid] - s + (float)nfill * fill;
    srow_s[tid] = v;
    Srow[g*DF + tid] = v;
  }
  for (int i = tid; i < K2C*DF; i += 256){
    int r = i / DF, d = i - r*DF;
    pooled[(size_t)g*PLEN + i] = feat_at(x1, x2, x3, x4, t27n[r], d);
  }
  __syncthreads();
  if (tid == 0){
    float t27sq = 0.f;
    for (int r = 0; r < K2C; r++) t27sq += sqv[t27n[r]];
    float sqfill = (float)DF * fill * fill;
    float Tsum = gstats[g*194 + 193] - t27sq + (float)nfill * sqfill;
    float ssum = 0.f;
    for (int d = 0; d < DF; d++) ssum += srow_s[d];
    float nf = (float)nv;
    float simfill = nf * sqfill + Tsum - 2.0f * fill * ssum;
    TS[g*2 + 0] = Tsum;
    TS[g*2 + 1] = simfill;
  }
}

// ---------------- per-node sim (coalesced) ----------------
__global__ __launch_bounds__(256) void k_sim(const float* __restrict__ x1, const float* __restrict__ x2,
                                             const float* __restrict__ x3, const float* __restrict__ x4,
                                             const float* __restrict__ sqv, const int* __restrict__ batch,
                                             const int* __restrict__ gcount, const int* __restrict__ rank,
                                             const float* __restrict__ Srow, const float* __restrict__ TS,
                                             float* __restrict__ sim, int NT){
  int wid  = blockIdx.x*4 + (threadIdx.x >> 6);
  int lane = threadIdx.x & 63;
  if (wid >= NT) return;
  if (rank[wid] < K2C) return;
  int g = batch[wid];
  float a = x1[(size_t)wid*64 + lane];
  float b = x2[(size_t)wid*64 + lane];
  float c = x3[(size_t)wid*64 + lane];
  float s1 = Srow[g*DF + lane];
  float s2 = Srow[g*DF + 64 + lane];
  float s3 = Srow[g*DF + 128 + lane];
  float dot = warp_sum64(a*s1 + b*s2 + c*s3);
  if (lane == 0){
    float d = x4[wid];
    dot += d * Srow[g*DF + 192];
    int n = gcount[g];
    float nf = (float)((n < NRESC) ? n : NRESC);
    sim[wid] = nf * sqv[wid] + TS[g*2] - 2.0f * dot;
  }
}

// ---------------- per-graph top-3 (parallel tree merge) + x_simi gather ----------------
DEV void top3_insert(float v, int j, float* tv, int* tj){
  if (v > tv[0] || (v == tv[0] && j < tj[0])){
    tv[2]=tv[1]; tj[2]=tj[1]; tv[1]=tv[0]; tj[1]=tj[0]; tv[0]=v; tj[0]=j;
  } else if (v > tv[1] || (v == tv[1] && j < tj[1])){
    tv[2]=tv[1]; tj[2]=tj[1]; tv[1]=v; tj[1]=j;
  } else if (v > tv[2] || (v == tv[2] && j < tj[2])){
    tv[2]=v; tj[2]=j;
  }
}
__global__ __launch_bounds__(256) void k_top3(const float* __restrict__ x1, const float* __restrict__ x2,
                                              const float* __restrict__ x3, const float* __restrict__ x4,
                                              const float* __restrict__ sim, const int* __restrict__ rank,
                                              const int* __restrict__ gcount, const int* __restrict__ goff,
                                              const int* __restrict__ sidxg, const float* __restrict__ TS,
                                              const float* __restrict__ minv, float* __restrict__ pooled){
  __shared__ float lv[256*3];
  __shared__ int   lj[256*3];
  __shared__ int   fsel[3];
  int g = blockIdx.x, tid = threadIdx.x;
  int n = gcount[g], base = goff[g];
  float fill = minv[0] - 1.0f;
  int nv = (n < NRESC) ? n : NRESC;
  int nreal = n - K2C;
  int nfill = nv - nreal;
  float tv[3] = {-FLT_MAX, -FLT_MAX, -FLT_MAX};
  int   tj[3] = {INT_MAX, INT_MAX, INT_MAX};
  for (int i = tid; i < n; i += 256){
    int node = base + i;
    int r = rank[node];
    if (r >= K2C) top3_insert(sim[node], r - K2C, tv, tj);
  }
#pragma unroll
  for (int q = 0; q < 3; q++){ lv[tid*3 + q] = tv[q]; lj[tid*3 + q] = tj[q]; }
  __syncthreads();
  for (int o = 128; o >= 1; o >>= 1){
    if (tid < o){
#pragma unroll
      for (int q = 0; q < 3; q++)
        top3_insert(lv[(tid + o)*3 + q], lj[(tid + o)*3 + q], tv, tj);
#pragma unroll
      for (int q = 0; q < 3; q++){ lv[tid*3 + q] = tv[q]; lj[tid*3 + q] = tj[q]; }
    }
    __syncthreads();
  }
  if (tid == 0){
    float simfill = TS[g*2 + 1];
    int ninj = (nfill < 3) ? nfill : 3;
    for (int q = 0; q < ninj; q++) top3_insert(simfill, nreal + q, tv, tj);
    fsel[0] = tj[0]; fsel[1] = tj[1]; fsel[2] = tj[2];
  }
  __syncthreads();
  for (int i = tid; i < K1C*DF; i += 256){
    int m = i / DF, d = i - m*DF;
    int j = fsel[m];
    float v;
    if (j < nreal){
      int node = base + sidxg[g*SORTN + K2C + j];
      v = feat_at(x1, x2, x3, x4, node, d);
    } else {
      v = fill;
    }
    pooled[(size_t)g*PLEN + K2C*DF + i] = v;
  }
}

// ---------------- conv5 + pairmax + conv6 (LDS-transposed weights, ILP4) ----
__global__ __launch_bounds__(256) void k_head(const float* __restrict__ pooled, const float* __restrict__ w5,
                                              const float* __restrict__ b5, const float* __restrict__ w6,
                                              const float* __restrict__ b6, float* __restrict__ h6){
  __shared__ float smem[21760];               // 87 KB
  float* pl  = smem;
  float* w5T = smem + 5790;
  float* h5  = smem + 18528;
  float* mx  = smem;
  float* w6T = smem + 960;
  int g = blockIdx.x, tid = threadIdx.x;
  for (int i = tid; i < PLEN; i += 256) pl[i] = pooled[(size_t)g*PLEN + i];
  for (int i = tid; i < 64*DF; i += 256){
    int o = i / DF, d = i - o*DF;
    w5T[d*66 + o] = w5[i];
  }
  __syncthreads();
  int o = tid & 63, tg = tid >> 6;
  for (int t = tg; t < 30; t += 4){
    const float* pr = &pl[t*DF];
    float a0=0.f, a1=0.f, a2=0.f, a3=0.f;
    for (int d = 0; d < 192; d += 4){
      a0 = fmaf(pr[d],   w5T[(d)*66 + o],   a0);
      a1 = fmaf(pr[d+1], w5T[(d+1)*66 + o], a1);
      a2 = fmaf(pr[d+2], w5T[(d+2)*66 + o], a2);
      a3 = fmaf(pr[d+3], w5T[(d+3)*66 + o], a3);
    }
    a0 = fmaf(pr[192], w5T[192*66 + o], a0);
    float acc = b5[o] + ((a0 + a1) + (a2 + a3));
    h5[t*64 + o] = fmaxf(acc, 0.f);
  }
  __syncthreads();
  for (int i = tid; i < 15*64; i += 256){
    int p = i >> 6, oo = i & 63;
    mx[i] = fmaxf(h5[(2*p)*64 + oo], h5[(2*p + 1)*64 + oo]);
  }
  __syncthreads();
  for (int i = tid; i < 64*64*5; i += 256){
    int oo = i / 320, rem = i - oo*320;
    w6T[rem*65 + oo] = w6[i];
  }
  __syncthreads();
  for (int t = tg; t < 11; t += 4){
    float a0=0.f, a1=0.f, a2=0.f, a3=0.f;
    for (int ii = 0; ii < 64; ii += 4){
#pragma unroll
      for (int k = 0; k < 5; k++){
        a0 = fmaf(mx[(t+k)*64 + ii],   w6T[((ii)*5   + k)*65 + o], a0);
        a1 = fmaf(mx[(t+k)*64 + ii+1], w6T[((ii+1)*5 + k)*65 + o], a1);
        a2 = fmaf(mx[(t+k)*64 + ii+2], w6T[((ii+2)*5 + k)*65 + o], a2);
        a3 = fmaf(mx[(t+k)*64 + ii+3], w6T[((ii+3)*5 + k)*65 + o], a3);
      }
    }
    float acc = b6[o] + ((a0 + a1) + (a2 + a3));
    h6[(size_t)g*704 + o*11 + t] = fmaxf(acc, 0.f);
  }
}

// ---------------- FC: 256 x 704 @ 704 x 1600, ReLU ----------------
__global__ __launch_bounds__(256) void k_fc(const float* __restrict__ h6, const float* __restrict__ fw,
                                            const float* __restrict__ fb, float* __restrict__ out){
  int j  = blockIdx.x*64 + (threadIdx.x & 63);
  int b0 = __builtin_amdgcn_readfirstlane(blockIdx.y*16 + (threadIdx.x >> 6)*4);
  const float* h0p = h6 + (size_t)b0*704;
  const float* h1p = h0p + 704;
  const float* h2p = h0p + 1408;
  const float* h3p = h0p + 2112;
  float a0e=0.f,a0o=0.f,a1e=0.f,a1o=0.f,a2e=0.f,a2o=0.f,a3e=0.f,a3o=0.f;
#pragma unroll 4
  for (int k = 0; k < 704; k += 2){
    float w0 = fw[(size_t)k*1600 + j];
    float w1 = fw[(size_t)k*1600 + 1600 + j];
    a0e = fmaf(h0p[k], w0, a0e); a0o = fmaf(h0p[k+1], w1, a0o);
    a1e = fmaf(h1p[k], w0, a1e); a1o = fmaf(h1p[k+1], w1, a1o);
    a2e = fmaf(h2p[k], w0, a2e); a2o = fmaf(h2p[k+1], w1, a2o);
    a3e = fmaf(h3p[k], w0, a3e); a3o = fmaf(h3p[k+1], w1, a3o);
  }
  float fbj = fb[j];
  out[(size_t)b0*1600 + j]       = fmaxf(a0e + a0o + fbj, 0.f);
  out[(size_t)(b0+1)*1600 + j]   = fmaxf(a1e + a1o + fbj, 0.f);
  out[(size_t)(b0+2)*1600 + j]   = fmaxf(a2e + a2o + fbj, 0.f);
  out[(size_t)(b0+3)*1600 + j]   = fmaxf(a3e + a3o + fbj, 0.f);
}

extern "C" void kernel_launch(void* const* d_in, const int* in_sizes, int n_in,
                              void* d_out, int out_size, void* d_ws, size_t ws_size,
                              hipStream_t stream){
  const float* x    = (const float*)d_in[0];
  const int*   ei   = (const int*)d_in[1];
  const int*   batch= (const int*)d_in[2];
  const float* W1 = (const float*)d_in[3];  const float* b1 = (const float*)d_in[4];
  const float* W2 = (const float*)d_in[5];  const float* b2 = (const float*)d_in[6];
  const float* W3 = (const float*)d_in[7];  const float* b3 = (const float*)d_in[8];
  const float* W4 = (const float*)d_in[9];  const float* b4 = (const float*)d_in[10];
  const float* w5 = (const float*)d_in[11]; const float* b5 = (const float*)d_in[12];
  const float* w6 = (const float*)d_in[13]; const float* b6 = (const float*)d_in[14];
  const float* fw = (const float*)d_in[15]; const float* fb = (const float*)d_in[16];
  float* out = (float*)d_out;

  const int NT = in_sizes[2];
  const int E  = in_sizes[1] / 2;
  const int epg = E / BG;
  const int* rows = ei;
  const int* cols = ei + E;

  char* ws = (char*)d_ws;
  size_t off = 0;
  auto alloc = [&](size_t bytes) -> char* {
    off = (off + 255) & ~(size_t)255;
    char* p = ws + off;
    off += bytes;
    return p;
  };

  int*      gcount  = (int*)     alloc(BG * 4);
  int*      goff    = (int*)     alloc((BG + 1) * 4);
  float*    minv    = (float*)   alloc(4);
  float*    bmin    = (float*)   alloc((size_t)BG * GPARTS * 4);
  float*    dis     = (float*)   alloc((size_t)NT * 4);
  int*      csr_off = (int*)     alloc((size_t)(NT + 1) * 4);
  int*      csr_src = (int*)     alloc((size_t)E * 4);
  float*    csr_w   = (float*)   alloc((size_t)E * 4);
  float*    HbufA   = (float*)   alloc((size_t)NT * 64 * 4);
  float*    HbufB   = (float*)   alloc((size_t)NT * 64 * 4);
  float*    x1      = (float*)   alloc((size_t)NT * 64 * 4);
  float*    x2      = (float*)   alloc((size_t)NT * 64 * 4);
  float*    x3      = (float*)   alloc((size_t)NT * 64 * 4);
  float*    x4      = (float*)   alloc((size_t)NT * 4);
  float*    H4      = (float*)   alloc((size_t)NT * 4);
  float*    sqv     = (float*)   alloc((size_t)NT * 4);
  float*    simv    = (float*)   alloc((size_t)NT * 4);
  int*      rank    = (int*)     alloc((size_t)NT * 4);
  int*      sidxg   = (int*)     alloc((size_t)BG * SORTN * 4);
  float*    gpart   = (float*)   alloc((size_t)BG * GPARTS * 194 * 4);
  float*    gstats  = (float*)   alloc((size_t)BG * 194 * 4);
  float*    Srow    = (float*)   alloc((size_t)BG * DF * 4);
  float*    TS      = (float*)   alloc((size_t)BG * 2 * 4);
  float*    pooled  = (float*)   alloc((size_t)BG * PLEN * 4);
  float*    h6      = (float*)   alloc((size_t)BG * 704 * 4);

  const int gridNT = (NT + 255) / 256;
  const int gridS  = (NT + 3) / 4;        // wave-per-node (k_sim)
  const int gridG  = (NT + 127) / 128;    // 128-row GEMM tiles

  k_bounds<<<gridNT, 256, 0, stream>>>(batch, goff, NT);
  k_gcount<<<1, 256, 0, stream>>>(goff, gcount);
  k_build<<<BG, 1024, 0, stream>>>(rows, cols, gcount, goff, dis, csr_off, csr_src, csr_w, NT, E, epg);

  // all layers: BK=64 low-register GEMM + LDS-staged agg
  k_gemm_lo<128><<<gridG, 256, 0, stream>>>(x, W1, HbufA, NT);
  k_aggL<false><<<BG, 1024, 0, stream>>>(HbufA, csr_off, csr_src, csr_w, dis, b1, W4, x1, H4, gcount, goff);
  k_gemm_lo<64><<<gridG, 256, 0, stream>>>(x1, W2, HbufB, NT);
  k_aggL<false><<<BG, 1024, 0, stream>>>(HbufB, csr_off, csr_src, csr_w, dis, b2, W4, x2, H4, gcount, goff);
  k_gemm_lo<64><<<gridG, 256, 0, stream>>>(x2, W3, HbufA, NT);
  k_aggL<true><<<BG, 1024, 0, stream>>>(HbufA, csr_off, csr_src, csr_w, dis, b3, W4, x3, H4, gcount, goff);
  k_agg1<<<gridNT, 256, 0, stream>>>(H4, csr_off, csr_src, csr_w, dis, b4, x4, NT);

  k_stats<<<dim3(BG, GPARTS), 256, 0, stream>>>(x1, x2, x3, x4, gcount, goff, sqv, gpart, bmin);
  k_min2<<<1, 256, 0, stream>>>(bmin, BG*GPARTS, minv);
  k_gcomb<<<BG, 256, 0, stream>>>(gpart, gstats);
  k_sort<<<BG, 256, 0, stream>>>(x4, gcount, goff, sidxg, rank);
  k_top27<<<BG, 256, 0, stream>>>(x1, x2, x3, x4, sqv, gcount, goff, sidxg, gstats, minv, Srow, TS, pooled);
  k_sim<<<gridS, 256, 0, stream>>>(x1, x2, x3, x4, sqv, batch, gcount, rank, Srow, TS, simv, NT);
  k_top3<<<BG, 256, 0, stream>>>(x1, x2, x3, x4, simv, rank, gcount, goff, sidxg, TS, minv, pooled);

  k_head<<<BG, 256, 0, stream>>>(pooled, w5, b5, w6, b6, h6);
  k_fc<<<dim3(25, 16), 256, 0, stream>>>(h6, fw, fb, out);
}